// Round 3
// baseline (283.929 us; speedup 1.0000x reference)
//
#include <hip/hip_runtime.h>
#include <cstdint>

typedef __bf16 bf16x8 __attribute__((ext_vector_type(8)));
typedef float f32x16 __attribute__((ext_vector_type(16)));

__device__ __forceinline__ unsigned short f2b(float f) {
    union { float f; uint32_t u; } x; x.f = f;
    uint32_t r = (x.u + 0x7fffu + ((x.u >> 16) & 1u)) >> 16;
    return (unsigned short)r;
}
__device__ __forceinline__ float b2f(unsigned short h) {
    union { float f; uint32_t u; } x; x.u = ((uint32_t)h) << 16;
    return x.f;
}

// Fragment-linear layout F(N,K): element (n,k) lives at
//   ((n>>5)*(K>>4) + (k>>4))*512 + (((k>>3)&1)*32 + (n&31))*8 + (k&7)
// so a wave's 32x32x16 B-fragment for (nblk, kstep) is one coalesced 1KB run:
//   base + (nblk*(K>>4)+kstep)*512 + lane*8, 8 elems per lane.
__device__ __forceinline__ long foff(int n, int k, int K) {
    return ((long)(n >> 5) * (K >> 4) + (k >> 4)) * 512 + (((k >> 3) & 1) * 32 + (n & 31)) * 8 + (k & 7);
}

// ---------------- convert x (fp32 -> bf16), row-major ----------------
__global__ __launch_bounds__(256) void convert_x_kernel(const float* __restrict__ x,
                                                        unsigned short* __restrict__ xb) {
    int i = (blockIdx.x * 256 + threadIdx.x) * 4;
    float4 v = *(const float4*)(x + i);
    ushort4 o;
    o.x = f2b(v.x); o.y = f2b(v.y); o.z = f2b(v.z); o.w = f2b(v.w);
    *(ushort4*)(xb + i) = o;
}

// ------- transpose+convert W[k][n] -> frag-linear Wf = F(3072, 1024) -------
__global__ __launch_bounds__(1024) void transpose_w_kernel(const float* __restrict__ Wq,
                                                           const float* __restrict__ Wk,
                                                           const float* __restrict__ Wv,
                                                           unsigned short* __restrict__ Wf) {
    __shared__ float tile[32][33];
    const float* W = (blockIdx.z == 0) ? Wq : (blockIdx.z == 1) ? Wk : Wv;
    int n0 = blockIdx.x * 32, k0 = blockIdx.y * 32;
    int tx = threadIdx.x, ty = threadIdx.y;
    tile[ty][tx] = W[(k0 + ty) * 1024 + n0 + tx];
    __syncthreads();
    int n = blockIdx.z * 1024 + n0 + ty;
    int k = k0 + tx;
    Wf[foff(n, k, 1024)] = f2b(tile[tx][ty]);
}

// ------------- flatmm-hybrid BT-form bf16 MFMA GEMM -------------
// C[m][n] = sum_k A[m][k] * B[n][k].  128x128 block tile, BK=64, 4 waves,
// wave-tile 64x64 (2x2 of v_mfma_f32_32x32x16_bf16).
// A: row-major global, staged to LDS via global_load_lds, XOR chunk swizzle,
//    DOUBLE-buffered with a single barrier per iteration (drain covers loads
//    issued one full compute phase earlier).
// B: frag-linear global (F layout), loaded straight to registers, coalesced,
//    no LDS, no barrier dependency -> interleaves with MFMA.
// EPI 0: QKV epilogue (bias; Q scaled row-major; K -> F(2048,1024)/batch;
//        V -> F(1024,2048)/batch)
// EPI 1: bf16 row-major S (ldc 2048)
// EPI 2: fp32 row-major out (ldc 1024)
template <int EPI>
__global__ __launch_bounds__(256) void gemm_fs(const unsigned short* __restrict__ A, int lda, long sA,
                                               const unsigned short* __restrict__ Bf, long sB,
                                               void* __restrict__ Cv, long sC, int K,
                                               const float* __restrict__ bq, const float* __restrict__ bk,
                                               const float* __restrict__ bv,
                                               unsigned short* __restrict__ Qb,
                                               unsigned short* __restrict__ Kf,
                                               unsigned short* __restrict__ Vf) {
    __shared__ unsigned short As[2][128 * 64];

    const int tid = threadIdx.x;
    const int wave = tid >> 6, lane = tid & 63;
    const int h = lane >> 5;
    const int l31 = lane & 31;
    const int wm = wave >> 1, wn = wave & 1;
    const long bm = (long)blockIdx.y * 128;
    const long bn = (long)blockIdx.x * 128;

    const unsigned short* Ab = A + (long)blockIdx.z * sA;
    const unsigned short* Bb = Bf + (long)blockIdx.z * sB;

    f32x16 acc[2][2];
#pragma unroll
    for (int mi = 0; mi < 2; ++mi)
#pragma unroll
        for (int ni = 0; ni < 2; ++ni)
#pragma unroll
            for (int r = 0; r < 16; ++r) acc[mi][ni][r] = 0.0f;

    // ---- A staging: wave stages rows {j*32 + wave*8 + (lane>>3)}, XOR chunk swizzle
    const int srow_in = lane >> 3;
    const int cswz = (lane & 7) ^ srow_in;
    const unsigned short* aptr[4];
    int asloff[4];
#pragma unroll
    for (int j = 0; j < 4; ++j) {
        const int row = j * 32 + wave * 8 + srow_in;
        aptr[j] = Ab + (bm + row) * (long)lda + cswz * 8;
        asloff[j] = (j * 32 + wave * 8) * 64;
    }

    // ---- B frag pointers (coalesced 1KB per (nblk,kstep))
    const unsigned short* bptr[2];
#pragma unroll
    for (int ni = 0; ni < 2; ++ni) {
        const long nblk = (bn >> 5) + wn * 2 + ni;
        bptr[ni] = Bb + nblk * (long)(K >> 4) * 512 + lane * 8;
    }

    // ---- A frag LDS offsets (phys chunk = logical ^ (row&7))
    int aoff[2][4];
#pragma unroll
    for (int mi = 0; mi < 2; ++mi)
#pragma unroll
        for (int kp = 0; kp < 4; ++kp)
            aoff[mi][kp] = (wm * 64 + mi * 32 + l31) * 64 + (((kp * 2 + h) ^ (l31 & 7)) * 8);

    const int nIter = K >> 6;

    // prologue: stage iter 0 into buf 0
#pragma unroll
    for (int j = 0; j < 4; ++j)
        __builtin_amdgcn_global_load_lds((const __attribute__((address_space(1))) void*)(aptr[j]),
                                         (__attribute__((address_space(3))) void*)&As[0][asloff[j]], 16, 0, 0);
    __syncthreads();

    for (int it = 0; it < nIter; ++it) {
        const int buf = it & 1;
        if (it + 1 < nIter) {
            const int koff = (it + 1) << 6;
#pragma unroll
            for (int j = 0; j < 4; ++j)
                __builtin_amdgcn_global_load_lds((const __attribute__((address_space(1))) void*)(aptr[j] + koff),
                                                 (__attribute__((address_space(3))) void*)&As[buf ^ 1][asloff[j]], 16, 0, 0);
        }
        // B frags for this iter: registers, no barrier dependency
        bf16x8 bfr[4][2];
#pragma unroll
        for (int kp = 0; kp < 4; ++kp)
#pragma unroll
            for (int ni = 0; ni < 2; ++ni)
                bfr[kp][ni] = *(const bf16x8*)(bptr[ni] + (long)(it * 4 + kp) * 512);
#pragma unroll
        for (int kp = 0; kp < 4; ++kp) {
            bf16x8 af[2];
#pragma unroll
            for (int mi = 0; mi < 2; ++mi)
                af[mi] = *(const bf16x8*)&As[buf][aoff[mi][kp]];
#pragma unroll
            for (int mi = 0; mi < 2; ++mi)
#pragma unroll
                for (int ni = 0; ni < 2; ++ni)
                    acc[mi][ni] = __builtin_amdgcn_mfma_f32_32x32x16_bf16(af[mi], bfr[kp][ni], acc[mi][ni], 0, 0, 0);
        }
        __syncthreads();   // drains staging for it+1 (issued one compute phase ago)
    }

    // ---- epilogue. 32x32 C/D layout: col = lane&31, row = (reg&3) + 8*(reg>>2) + 4*(lane>>5)
#pragma unroll
    for (int mi = 0; mi < 2; ++mi) {
#pragma unroll
        for (int ni = 0; ni < 2; ++ni) {
            const f32x16 a = acc[mi][ni];
            const long col = bn + wn * 64 + ni * 32 + l31;
            const long rowB = bm + wm * 64 + mi * 32 + h * 4;
            if constexpr (EPI == 0) {
                if (col < 1024) {
                    const float bias = bq[col];
#pragma unroll
                    for (int g = 0; g < 4; ++g)
#pragma unroll
                        for (int r = 0; r < 4; ++r)
                            Qb[(rowB + g * 8 + r) * 1024 + col] = f2b((a[g * 4 + r] + bias) * 0.03125f);
                } else if (col < 2048) {
                    // K -> F(2048 tokens, 1024 e) per batch
                    const int e = (int)col - 1024;
                    const float bias = bk[e];
                    const long batch = rowB >> 11;
                    const int tokB = (int)(rowB & 2047) & ~31;   // 32-aligned token block
                    unsigned short* dst = Kf + batch * (2048L * 1024) +
                                          ((long)(tokB >> 5) * 64 + (e >> 4)) * 512 +
                                          (long)(((e >> 3) & 1) * 32) * 8 + (e & 7);
#pragma unroll
                    for (int g = 0; g < 4; ++g)
#pragma unroll
                        for (int r = 0; r < 4; ++r) {
                            const int tok31 = (int)((rowB + g * 8 + r) & 31);
                            dst[tok31 * 8] = f2b(a[g * 4 + r] + bias);
                        }
                } else {
                    // V -> F(1024 e, 2048 tokens) per batch
                    const int e = (int)col - 2048;
                    const float bias = bv[e];
                    const long batch = rowB >> 11;
                    unsigned short* base = Vf + batch * (2048L * 1024) + (long)(e >> 5) * 128 * 512 + l31 * 8;
#pragma unroll
                    for (int g = 0; g < 4; ++g)
#pragma unroll
                        for (int r = 0; r < 4; ++r) {
                            const int tok = (int)((rowB + g * 8 + r) & 2047);
                            base[((long)(tok >> 4)) * 512 + (long)(((tok >> 3) & 1) * 32) * 8 + (tok & 7)] =
                                f2b(a[g * 4 + r] + bias);
                        }
                }
            } else if constexpr (EPI == 1) {
                unsigned short* S = (unsigned short*)Cv + (long)blockIdx.z * sC;
#pragma unroll
                for (int g = 0; g < 4; ++g)
#pragma unroll
                    for (int r = 0; r < 4; ++r)
                        S[(rowB + g * 8 + r) * 2048 + col] = f2b(a[g * 4 + r]);
            } else {
                float* O = (float*)Cv + (long)blockIdx.z * sC;
#pragma unroll
                for (int g = 0; g < 4; ++g)
#pragma unroll
                    for (int r = 0; r < 4; ++r)
                        O[(rowB + g * 8 + r) * 1024 + col] = a[g * 4 + r];
            }
        }
    }
}

// ---------------- row softmax over 2048 bf16, in place ----------------
__global__ __launch_bounds__(256) void softmax_kernel(unsigned short* __restrict__ S) {
    const long row = blockIdx.x;
    unsigned short* p = S + row * 2048;
    const int tid = threadIdx.x;
    const int wave = tid >> 6, lane = tid & 63;

    ushort4 u0 = *(const ushort4*)&p[tid * 8];
    ushort4 u1 = *(const ushort4*)&p[tid * 8 + 4];
    float v[8];
    v[0] = b2f(u0.x); v[1] = b2f(u0.y); v[2] = b2f(u0.z); v[3] = b2f(u0.w);
    v[4] = b2f(u1.x); v[5] = b2f(u1.y); v[6] = b2f(u1.z); v[7] = b2f(u1.w);

    float m = v[0];
#pragma unroll
    for (int j = 1; j < 8; ++j) m = fmaxf(m, v[j]);
#pragma unroll
    for (int off = 32; off; off >>= 1) m = fmaxf(m, __shfl_xor(m, off, 64));
    __shared__ float redm[4];
    __shared__ float reds[4];
    if (lane == 0) redm[wave] = m;
    __syncthreads();
    m = fmaxf(fmaxf(redm[0], redm[1]), fmaxf(redm[2], redm[3]));

    float s = 0.0f;
#pragma unroll
    for (int j = 0; j < 8; ++j) { v[j] = __expf(v[j] - m); s += v[j]; }
#pragma unroll
    for (int off = 32; off; off >>= 1) s += __shfl_xor(s, off, 64);
    if (lane == 0) reds[wave] = s;
    __syncthreads();
    s = reds[0] + reds[1] + reds[2] + reds[3];
    const float inv = 1.0f / s;

    u0.x = f2b(v[0] * inv); u0.y = f2b(v[1] * inv); u0.z = f2b(v[2] * inv); u0.w = f2b(v[3] * inv);
    u1.x = f2b(v[4] * inv); u1.y = f2b(v[5] * inv); u1.z = f2b(v[6] * inv); u1.w = f2b(v[7] * inv);
    *(ushort4*)&p[tid * 8] = u0;
    *(ushort4*)&p[tid * 8 + 4] = u1;
}

extern "C" void kernel_launch(void* const* d_in, const int* in_sizes, int n_in,
                              void* d_out, int out_size, void* d_ws, size_t ws_size,
                              hipStream_t stream) {
    const float* x  = (const float*)d_in[0];
    const float* Wq = (const float*)d_in[1];
    const float* Wk = (const float*)d_in[2];
    const float* Wv = (const float*)d_in[3];
    const float* bq = (const float*)d_in[4];
    const float* bk = (const float*)d_in[5];
    const float* bv = (const float*)d_in[6];
    float* out = (float*)d_out;

    char* ws = (char*)d_ws;
    unsigned short* xb = (unsigned short*)ws; ws += 8192L * 1024 * 2;   // row-major
    unsigned short* Wf = (unsigned short*)ws; ws += 3072L * 1024 * 2;   // F(3072,1024)
    unsigned short* Qb = (unsigned short*)ws; ws += 8192L * 1024 * 2;   // row-major
    unsigned short* Kf = (unsigned short*)ws; ws += 8192L * 1024 * 2;   // F(2048,1024) x4
    unsigned short* Vf = (unsigned short*)ws; ws += 8192L * 1024 * 2;   // F(1024,2048) x4
    unsigned short* S  = (unsigned short*)ws; ws += 4L * 2048 * 2048 * 2;

    convert_x_kernel<<<8192, 256, 0, stream>>>(x, xb);
    transpose_w_kernel<<<dim3(32, 32, 3), dim3(32, 32), 0, stream>>>(Wq, Wk, Wv, Wf);
    // QKV projection: [8192,3072] = xb @ Wf^T (+bias; Q scaled; K,V frag-packed)
    gemm_fs<0><<<dim3(24, 64, 1), 256, 0, stream>>>(xb, 1024, 0, Wf, 0,
                                                    nullptr, 0, 1024, bq, bk, bv, Qb, Kf, Vf);
    // S[b] = Q[b] @ K[b]^T (Q pre-scaled by 1/32)
    gemm_fs<1><<<dim3(16, 16, 4), 256, 0, stream>>>(Qb, 1024, 2048L * 1024, Kf, 2048L * 1024,
                                                    S, 2048L * 2048, 1024,
                                                    nullptr, nullptr, nullptr, nullptr, nullptr, nullptr);
    softmax_kernel<<<8192, 256, 0, stream>>>(S);
    // out[b] = P[b] @ Vf[b]^T (fp32 out)
    gemm_fs<2><<<dim3(8, 16, 4), 256, 0, stream>>>(S, 2048, 2048L * 2048, Vf, 2048L * 1024,
                                                   out, 2048L * 1024, 2048,
                                                   nullptr, nullptr, nullptr, nullptr, nullptr, nullptr);
}

// Round 4
// 281.376 us; speedup vs baseline: 1.0091x; 1.0091x over previous
//
#include <hip/hip_runtime.h>
#include <cstdint>

typedef __bf16 bf16x8 __attribute__((ext_vector_type(8)));
typedef float f32x16 __attribute__((ext_vector_type(16)));

__device__ __forceinline__ unsigned short f2b(float f) {
    union { float f; uint32_t u; } x; x.f = f;
    uint32_t r = (x.u + 0x7fffu + ((x.u >> 16) & 1u)) >> 16;
    return (unsigned short)r;
}
__device__ __forceinline__ float b2f(unsigned short h) {
    union { float f; uint32_t u; } x; x.u = ((uint32_t)h) << 16;
    return x.f;
}

// Fragment-linear layout F(N,K): element (n,k) lives at
//   ((n>>5)*(K>>4) + (k>>4))*512 + (((k>>3)&1)*32 + (n&31))*8 + (k&7)
// so a wave's 32x32x16 B-fragment for (nblk, kstep) is one coalesced 1KB run:
//   base + (nblk*(K>>4)+kstep)*512 + lane*8, 8 elems per lane.
__device__ __forceinline__ long foff(int n, int k, int K) {
    return ((long)(n >> 5) * (K >> 4) + (k >> 4)) * 512 + (((k >> 3) & 1) * 32 + (n & 31)) * 8 + (k & 7);
}

// ---------------- convert x (fp32 -> bf16), row-major ----------------
__global__ __launch_bounds__(256) void convert_x_kernel(const float* __restrict__ x,
                                                        unsigned short* __restrict__ xb) {
    int i = (blockIdx.x * 256 + threadIdx.x) * 4;
    float4 v = *(const float4*)(x + i);
    ushort4 o;
    o.x = f2b(v.x); o.y = f2b(v.y); o.z = f2b(v.z); o.w = f2b(v.w);
    *(ushort4*)(xb + i) = o;
}

// ------- transpose+convert W[k][n] -> frag-linear Wf = F(3072, 1024) -------
__global__ __launch_bounds__(1024) void transpose_w_kernel(const float* __restrict__ Wq,
                                                           const float* __restrict__ Wk,
                                                           const float* __restrict__ Wv,
                                                           unsigned short* __restrict__ Wf) {
    __shared__ float tile[32][33];
    const float* W = (blockIdx.z == 0) ? Wq : (blockIdx.z == 1) ? Wk : Wv;
    int n0 = blockIdx.x * 32, k0 = blockIdx.y * 32;
    int tx = threadIdx.x, ty = threadIdx.y;
    tile[ty][tx] = W[(k0 + ty) * 1024 + n0 + tx];
    __syncthreads();
    int n = blockIdx.z * 1024 + n0 + ty;
    int k = k0 + tx;
    Wf[foff(n, k, 1024)] = f2b(tile[tx][ty]);
}

// ------------- flatmm-hybrid BT-form bf16 MFMA GEMM -------------
// C[m][n] = sum_k A[m][k] * B[n][k].  128x128 block tile, BK=64, 4 waves,
// wave-tile 64x64 (2x2 of v_mfma_f32_32x32x16_bf16).
// A: row-major global, staged to LDS (global_load_lds, XOR chunk swizzle),
//    double-buffered, one barrier per iteration.
// B: frag-linear global, loaded straight to registers.
// CRITICAL ORDER (vmcnt is FIFO): B-frag loads for THIS iteration are issued
// BEFORE the staging loads for it+1, so the MFMA's vmcnt wait on B does NOT
// drain the staging; staging completes during the compute phase and is only
// drained at the barrier. sched_barrier(0) pins the issue order.
// EPI 0: QKV epilogue (bias; Q scaled row-major; K -> F(2048,1024)/batch;
//        V -> F(1024,2048)/batch)
// EPI 1: bf16 row-major S (ldc 2048)
// EPI 2: fp32 row-major out (ldc 1024)
template <int EPI>
__global__ __launch_bounds__(256) void gemm_fs(const unsigned short* __restrict__ A, int lda, long sA,
                                               const unsigned short* __restrict__ Bf, long sB,
                                               void* __restrict__ Cv, long sC, int K,
                                               const float* __restrict__ bq, const float* __restrict__ bk,
                                               const float* __restrict__ bv,
                                               unsigned short* __restrict__ Qb,
                                               unsigned short* __restrict__ Kf,
                                               unsigned short* __restrict__ Vf) {
    __shared__ unsigned short As[2][128 * 64];

    const int tid = threadIdx.x;
    const int wave = tid >> 6, lane = tid & 63;
    const int h = lane >> 5;
    const int l31 = lane & 31;
    const int wm = wave >> 1, wn = wave & 1;
    const long bm = (long)blockIdx.y * 128;
    const long bn = (long)blockIdx.x * 128;

    const unsigned short* Ab = A + (long)blockIdx.z * sA;
    const unsigned short* Bb = Bf + (long)blockIdx.z * sB;

    f32x16 acc[2][2];
#pragma unroll
    for (int mi = 0; mi < 2; ++mi)
#pragma unroll
        for (int ni = 0; ni < 2; ++ni)
#pragma unroll
            for (int r = 0; r < 16; ++r) acc[mi][ni][r] = 0.0f;

    // ---- A staging: wave stages rows {j*32 + wave*8 + (lane>>3)}, XOR chunk swizzle
    const int srow_in = lane >> 3;
    const int cswz = (lane & 7) ^ srow_in;
    const unsigned short* aptr[4];
    int asloff[4];
#pragma unroll
    for (int j = 0; j < 4; ++j) {
        const int row = j * 32 + wave * 8 + srow_in;
        aptr[j] = Ab + (bm + row) * (long)lda + cswz * 8;
        asloff[j] = (j * 32 + wave * 8) * 64;
    }

    // ---- B frag pointers (coalesced 1KB per (nblk,kstep))
    const unsigned short* bptr[2];
#pragma unroll
    for (int ni = 0; ni < 2; ++ni) {
        const long nblk = (bn >> 5) + wn * 2 + ni;
        bptr[ni] = Bb + nblk * (long)(K >> 4) * 512 + lane * 8;
    }

    // ---- A frag LDS offsets (phys chunk = logical ^ (row&7))
    int aoff[2][4];
#pragma unroll
    for (int mi = 0; mi < 2; ++mi)
#pragma unroll
        for (int kp = 0; kp < 4; ++kp)
            aoff[mi][kp] = (wm * 64 + mi * 32 + l31) * 64 + (((kp * 2 + h) ^ (l31 & 7)) * 8);

    const int nIter = K >> 6;

    // prologue: stage iter 0 into buf 0
#pragma unroll
    for (int j = 0; j < 4; ++j)
        __builtin_amdgcn_global_load_lds((const __attribute__((address_space(1))) void*)(aptr[j]),
                                         (__attribute__((address_space(3))) void*)&As[0][asloff[j]], 16, 0, 0);
    __syncthreads();

    for (int it = 0; it < nIter; ++it) {
        const int buf = it & 1;
        // 1) B frags for THIS iteration -- issued first so their vmcnt wait
        //    does not cover the staging below.
        bf16x8 bfr[4][2];
#pragma unroll
        for (int kp = 0; kp < 4; ++kp)
#pragma unroll
            for (int ni = 0; ni < 2; ++ni)
                bfr[kp][ni] = *(const bf16x8*)(bptr[ni] + (long)(it * 4 + kp) * 512);
        __builtin_amdgcn_sched_barrier(0);
        // 2) stage A for it+1 (drained only at the barrier)
        if (it + 1 < nIter) {
            const int koff = (it + 1) << 6;
#pragma unroll
            for (int j = 0; j < 4; ++j)
                __builtin_amdgcn_global_load_lds((const __attribute__((address_space(1))) void*)(aptr[j] + koff),
                                                 (__attribute__((address_space(3))) void*)&As[buf ^ 1][asloff[j]], 16, 0, 0);
        }
        __builtin_amdgcn_sched_barrier(0);
        // 3) compute on buf
#pragma unroll
        for (int kp = 0; kp < 4; ++kp) {
            bf16x8 af[2];
#pragma unroll
            for (int mi = 0; mi < 2; ++mi)
                af[mi] = *(const bf16x8*)&As[buf][aoff[mi][kp]];
#pragma unroll
            for (int mi = 0; mi < 2; ++mi)
#pragma unroll
                for (int ni = 0; ni < 2; ++ni)
                    acc[mi][ni] = __builtin_amdgcn_mfma_f32_32x32x16_bf16(af[mi], bfr[kp][ni], acc[mi][ni], 0, 0, 0);
        }
        __syncthreads();
    }

    // ---- epilogue. 32x32 C/D layout: col = lane&31, row = (reg&3) + 8*(reg>>2) + 4*(lane>>5)
#pragma unroll
    for (int mi = 0; mi < 2; ++mi) {
#pragma unroll
        for (int ni = 0; ni < 2; ++ni) {
            const f32x16 a = acc[mi][ni];
            const long col = bn + wn * 64 + ni * 32 + l31;
            const long rowB = bm + wm * 64 + mi * 32 + h * 4;
            if constexpr (EPI == 0) {
                if (col < 1024) {
                    const float bias = bq[col];
#pragma unroll
                    for (int g = 0; g < 4; ++g)
#pragma unroll
                        for (int r = 0; r < 4; ++r)
                            Qb[(rowB + g * 8 + r) * 1024 + col] = f2b((a[g * 4 + r] + bias) * 0.03125f);
                } else if (col < 2048) {
                    // K -> F(2048 tokens, 1024 e) per batch
                    const int e = (int)col - 1024;
                    const float bias = bk[e];
                    const long batch = rowB >> 11;
                    const int tokB = (int)(rowB & 2047) & ~31;   // 32-aligned token block
                    unsigned short* dst = Kf + batch * (2048L * 1024) +
                                          ((long)(tokB >> 5) * 64 + (e >> 4)) * 512 +
                                          (long)(((e >> 3) & 1) * 32) * 8 + (e & 7);
#pragma unroll
                    for (int g = 0; g < 4; ++g)
#pragma unroll
                        for (int r = 0; r < 4; ++r) {
                            const int tok31 = (int)((rowB + g * 8 + r) & 31);
                            dst[tok31 * 8] = f2b(a[g * 4 + r] + bias);
                        }
                } else {
                    // V -> F(1024 e, 2048 tokens) per batch
                    const int e = (int)col - 2048;
                    const float bias = bv[e];
                    const long batch = rowB >> 11;
                    unsigned short* base = Vf + batch * (2048L * 1024) + (long)(e >> 5) * 128 * 512 + l31 * 8;
#pragma unroll
                    for (int g = 0; g < 4; ++g)
#pragma unroll
                        for (int r = 0; r < 4; ++r) {
                            const int tok = (int)((rowB + g * 8 + r) & 2047);
                            base[((long)(tok >> 4)) * 512 + (long)(((tok >> 3) & 1) * 32) * 8 + (tok & 7)] =
                                f2b(a[g * 4 + r] + bias);
                        }
                }
            } else if constexpr (EPI == 1) {
                unsigned short* S = (unsigned short*)Cv + (long)blockIdx.z * sC;
#pragma unroll
                for (int g = 0; g < 4; ++g)
#pragma unroll
                    for (int r = 0; r < 4; ++r)
                        S[(rowB + g * 8 + r) * 2048 + col] = f2b(a[g * 4 + r]);
            } else {
                float* O = (float*)Cv + (long)blockIdx.z * sC;
#pragma unroll
                for (int g = 0; g < 4; ++g)
#pragma unroll
                    for (int r = 0; r < 4; ++r)
                        O[(rowB + g * 8 + r) * 1024 + col] = a[g * 4 + r];
            }
        }
    }
}

// ---------------- row softmax over 2048 bf16, in place ----------------
__global__ __launch_bounds__(256) void softmax_kernel(unsigned short* __restrict__ S) {
    const long row = blockIdx.x;
    unsigned short* p = S + row * 2048;
    const int tid = threadIdx.x;
    const int wave = tid >> 6, lane = tid & 63;

    ushort4 u0 = *(const ushort4*)&p[tid * 8];
    ushort4 u1 = *(const ushort4*)&p[tid * 8 + 4];
    float v[8];
    v[0] = b2f(u0.x); v[1] = b2f(u0.y); v[2] = b2f(u0.z); v[3] = b2f(u0.w);
    v[4] = b2f(u1.x); v[5] = b2f(u1.y); v[6] = b2f(u1.z); v[7] = b2f(u1.w);

    float m = v[0];
#pragma unroll
    for (int j = 1; j < 8; ++j) m = fmaxf(m, v[j]);
#pragma unroll
    for (int off = 32; off; off >>= 1) m = fmaxf(m, __shfl_xor(m, off, 64));
    __shared__ float redm[4];
    __shared__ float reds[4];
    if (lane == 0) redm[wave] = m;
    __syncthreads();
    m = fmaxf(fmaxf(redm[0], redm[1]), fmaxf(redm[2], redm[3]));

    float s = 0.0f;
#pragma unroll
    for (int j = 0; j < 8; ++j) { v[j] = __expf(v[j] - m); s += v[j]; }
#pragma unroll
    for (int off = 32; off; off >>= 1) s += __shfl_xor(s, off, 64);
    if (lane == 0) reds[wave] = s;
    __syncthreads();
    s = reds[0] + reds[1] + reds[2] + reds[3];
    const float inv = 1.0f / s;

    u0.x = f2b(v[0] * inv); u0.y = f2b(v[1] * inv); u0.z = f2b(v[2] * inv); u0.w = f2b(v[3] * inv);
    u1.x = f2b(v[4] * inv); u1.y = f2b(v[5] * inv); u1.z = f2b(v[6] * inv); u1.w = f2b(v[7] * inv);
    *(ushort4*)&p[tid * 8] = u0;
    *(ushort4*)&p[tid * 8 + 4] = u1;
}

extern "C" void kernel_launch(void* const* d_in, const int* in_sizes, int n_in,
                              void* d_out, int out_size, void* d_ws, size_t ws_size,
                              hipStream_t stream) {
    const float* x  = (const float*)d_in[0];
    const float* Wq = (const float*)d_in[1];
    const float* Wk = (const float*)d_in[2];
    const float* Wv = (const float*)d_in[3];
    const float* bq = (const float*)d_in[4];
    const float* bk = (const float*)d_in[5];
    const float* bv = (const float*)d_in[6];
    float* out = (float*)d_out;

    char* ws = (char*)d_ws;
    unsigned short* xb = (unsigned short*)ws; ws += 8192L * 1024 * 2;   // row-major
    unsigned short* Wf = (unsigned short*)ws; ws += 3072L * 1024 * 2;   // F(3072,1024)
    unsigned short* Qb = (unsigned short*)ws; ws += 8192L * 1024 * 2;   // row-major
    unsigned short* Kf = (unsigned short*)ws; ws += 8192L * 1024 * 2;   // F(2048,1024) x4
    unsigned short* Vf = (unsigned short*)ws; ws += 8192L * 1024 * 2;   // F(1024,2048) x4
    unsigned short* S  = (unsigned short*)ws; ws += 4L * 2048 * 2048 * 2;

    convert_x_kernel<<<8192, 256, 0, stream>>>(x, xb);
    transpose_w_kernel<<<dim3(32, 32, 3), dim3(32, 32), 0, stream>>>(Wq, Wk, Wv, Wf);
    // QKV projection: [8192,3072] = xb @ Wf^T (+bias; Q scaled; K,V frag-packed)
    gemm_fs<0><<<dim3(24, 64, 1), 256, 0, stream>>>(xb, 1024, 0, Wf, 0,
                                                    nullptr, 0, 1024, bq, bk, bv, Qb, Kf, Vf);
    // S[b] = Q[b] @ K[b]^T (Q pre-scaled by 1/32)
    gemm_fs<1><<<dim3(16, 16, 4), 256, 0, stream>>>(Qb, 1024, 2048L * 1024, Kf, 2048L * 1024,
                                                    S, 2048L * 2048, 1024,
                                                    nullptr, nullptr, nullptr, nullptr, nullptr, nullptr);
    softmax_kernel<<<8192, 256, 0, stream>>>(S);
    // out[b] = P[b] @ Vf[b]^T (fp32 out)
    gemm_fs<2><<<dim3(8, 16, 4), 256, 0, stream>>>(S, 2048, 2048L * 2048, Vf, 2048L * 1024,
                                                   out, 2048L * 1024, 2048,
                                                   nullptr, nullptr, nullptr, nullptr, nullptr, nullptr);
}